// Round 13
// baseline (216.149 us; speedup 1.0000x reference)
//
#include <hip/hip_runtime.h>
#include <hip/hip_bf16.h>
#include <hip/hip_fp16.h>

typedef _Float16 f16;
typedef _Float16 f16x4 __attribute__((ext_vector_type(4)));
typedef _Float16 f16x8 __attribute__((ext_vector_type(8)));
typedef float f32x4 __attribute__((ext_vector_type(4)));

#define MFMA16(a, b, c) __builtin_amdgcn_mfma_f32_16x16x32_f16(a, b, c, 0, 0, 0)

__device__ __forceinline__ float fexp2(float x) {
#if __has_builtin(__builtin_amdgcn_exp2f)
    return __builtin_amdgcn_exp2f(x);
#else
    return exp2f(x);
#endif
}

typedef __attribute__((address_space(1))) const void gconst_t;
typedef __attribute__((address_space(3))) void lds_t;
__device__ __forceinline__ void gload16(const f16* g, f16* l) {
    __builtin_amdgcn_global_load_lds((gconst_t*)g, (lds_t*)l, 16, 0, 0);
}

// ---------------- prep: f32 -> f16 convert ----------------
__global__ void k_convert_x(const float* __restrict__ in, f16* __restrict__ out, int n4) {
    int i = blockIdx.x * blockDim.x + threadIdx.x;
    if (i >= n4) return;
    float4 v = ((const float4*)in)[i];
    f16x4 o = {(f16)v.x, (f16)v.y, (f16)v.z, (f16)v.w};
    ((f16x4*)out)[i] = o;
}

// ---------------- prep: transpose f32[K][N] -> f16[N][K] ----------------
__global__ __launch_bounds__(256) void k_transpose(const float* __restrict__ in,
                                                   f16* __restrict__ out, int K, int N) {
    __shared__ f16 tile[64][72];
    int n0 = blockIdx.x * 64, k0 = blockIdx.y * 64;
    int t = threadIdx.x;
    int r = t >> 2, cb = (t & 3) * 16;
    const float* src = in + (size_t)(k0 + r) * N + n0 + cb;
#pragma unroll
    for (int j = 0; j < 4; ++j) {
        float4 v = ((const float4*)src)[j];
        tile[r][cb + 4 * j + 0] = (f16)v.x;
        tile[r][cb + 4 * j + 1] = (f16)v.y;
        tile[r][cb + 4 * j + 2] = (f16)v.z;
        tile[r][cb + 4 * j + 3] = (f16)v.w;
    }
    __syncthreads();
    int nl = t >> 2, kb = (t & 3) * 16;
    f16* dst = out + (size_t)(n0 + nl) * K + k0 + kb;
#pragma unroll
    for (int j = 0; j < 2; ++j) {
        f16x8 o;
#pragma unroll
        for (int e = 0; e < 8; ++e) o[e] = tile[kb + 8 * j + e][nl];
        *(f16x8*)(dst + 8 * j) = o;
    }
}

// ---------------- shared GEMM core (R8): global_load_lds + XOR-swizzled LDS ----------------
__device__ __forceinline__ void gemm_core(const f16* __restrict__ A, const f16* __restrict__ Bt,
                                          int m0, int n0, int lane, int w, int wr, int wc,
                                          f16* As, f16* Bs, f32x4 acc[4][4]) {
    int prow = lane >> 2, pc = lane & 3;
    int lrow = prow ^ ((prow >> 2) & 1);
    int lcol = (pc ^ (lrow & 3)) * 8;
    int rsw = (lane & 7) << 3;
    for (int kt = 0; kt < 24; ++kt) {
        const f16* ab = A + (size_t)(m0 + w * 32 + lrow) * 768 + kt * 32 + lcol;
        const f16* bb = Bt + (size_t)(n0 + w * 32 + lrow) * 768 + kt * 32 + lcol;
        gload16(ab, As + (w * 32) * 32);
        gload16(ab + (size_t)16 * 768, As + (w * 32 + 16) * 32);
        gload16(bb, Bs + (w * 32) * 32);
        gload16(bb + (size_t)16 * 768, Bs + (w * 32 + 16) * 32);
        __syncthreads();
        f16x8 a[4], b[4];
#pragma unroll
        for (int i = 0; i < 4; ++i) {
            int idx = (wr * 64 + i * 16 + (lane & 15)) * 32 + (lane >> 4) * 8;
            a[i] = *(const f16x8*)(As + (idx ^ rsw));
        }
#pragma unroll
        for (int j = 0; j < 4; ++j) {
            int idx = (wc * 64 + j * 16 + (lane & 15)) * 32 + (lane >> 4) * 8;
            b[j] = *(const f16x8*)(Bs + (idx ^ rsw));
        }
#pragma unroll
        for (int i = 0; i < 4; ++i)
#pragma unroll
            for (int j = 0; j < 4; ++j) acc[i][j] = MFMA16(a[i], b[j], acc[i][j]);
        __syncthreads();
    }
}

// ---------------- QKV GEMM -> Qh (row layout), Kf/Vf (fragment-linear) ----------------
__global__ __launch_bounds__(256) void k_qkv_gemm(const f16* __restrict__ A, const f16* __restrict__ Bt,
                                                  const float* __restrict__ bias,
                                                  f16* __restrict__ Qh, f16* __restrict__ Kf,
                                                  f16* __restrict__ Vf) {
    __shared__ __align__(16) f16 As[128 * 32];
    __shared__ __align__(16) f16 Bs[128 * 32];
    int m0 = blockIdx.x * 128, n0 = blockIdx.y * 128;
    int t = threadIdx.x, lane = t & 63, w = t >> 6;
    int wr = w >> 1, wc = w & 1;
    f32x4 zero = {0.f, 0.f, 0.f, 0.f};
    f32x4 acc[4][4];
#pragma unroll
    for (int i = 0; i < 4; ++i)
#pragma unroll
        for (int j = 0; j < 4; ++j) acc[i][j] = zero;

    gemm_core(A, Bt, m0, n0, lane, w, wr, wc, As, Bs, acc);

    const float QSCALE = 0.18033688011112042f;  // 0.125 * log2(e)
#pragma unroll
    for (int j = 0; j < 4; ++j) {
        int n = n0 + wc * 64 + j * 16 + (lane & 15);
        int which = n / 768;
        int rem = n - which * 768;
        int h = rem >> 6, d = rem & 63;
        float bv = bias[n];
#pragma unroll
        for (int i = 0; i < 4; ++i) {
            int m = m0 + wr * 64 + i * 16 + ((lane >> 4) << 2);
            int bb = m >> 11, tt = m & 2047;
            int bh = bb * 12 + h;
            if (which == 2) {
                int kt = tt >> 6;
                int half = (tt & 63) >> 5, hi = (tt & 31) >> 3, e0 = tt & 7;
                int jd = d >> 4, lo = d & 15;
                size_t addr = (((size_t)bh * 32 + kt) * 8 + jd * 2 + half) * 512 +
                              (size_t)(hi * 16 + lo) * 8 + e0;
                f16x4 pk;
#pragma unroll
                for (int r = 0; r < 4; ++r) pk[r] = (f16)(acc[i][j][r] + bv);
                *(f16x4*)(Vf + addr) = pk;
            } else if (which == 0) {
#pragma unroll
                for (int r = 0; r < 4; ++r)
                    Qh[((size_t)bh * 2048 + tt + r) * 64 + d] = (f16)((acc[i][j][r] + bv) * QSCALE);
            } else {
                int half = d >> 5, hi = (d & 31) >> 3, e = d & 7;
#pragma unroll
                for (int r = 0; r < 4; ++r) {
                    int tr = tt + r;
                    int kt = tr >> 6, row = tr & 63;
                    int s = row >> 4, lo = row & 15;
                    size_t addr = (((size_t)bh * 32 + kt) * 8 + s * 2 + half) * 512 +
                                  (size_t)(hi * 16 + lo) * 8 + e;
                    Kf[addr] = (f16)(acc[i][j][r] + bv);
                }
            }
        }
    }
}

// ---------------- O GEMM ----------------
__global__ __launch_bounds__(256) void k_o_gemm(const f16* __restrict__ A, const f16* __restrict__ Bt,
                                                const float* __restrict__ bias,
                                                float* __restrict__ out) {
    __shared__ __align__(16) f16 As[128 * 32];
    __shared__ __align__(16) f16 Bs[128 * 32];
    int m0 = blockIdx.x * 128, n0 = blockIdx.y * 128;
    int t = threadIdx.x, lane = t & 63, w = t >> 6;
    int wr = w >> 1, wc = w & 1;
    f32x4 zero = {0.f, 0.f, 0.f, 0.f};
    f32x4 acc[4][4];
#pragma unroll
    for (int i = 0; i < 4; ++i)
#pragma unroll
        for (int j = 0; j < 4; ++j) acc[i][j] = zero;

    gemm_core(A, Bt, m0, n0, lane, w, wr, wc, As, Bs, acc);

#pragma unroll
    for (int j = 0; j < 4; ++j) {
        int n = n0 + wc * 64 + j * 16 + (lane & 15);
        float bv = bias[n];
#pragma unroll
        for (int i = 0; i < 4; ++i) {
            int m = m0 + wr * 64 + i * 16 + ((lane >> 4) << 2);
#pragma unroll
            for (int r = 0; r < 4; ++r) out[(size_t)(m + r) * 768 + n] = acc[i][j][r] + bv;
        }
    }
}

// ---------------- lsum: split-k partial row-sums, swapped QK^T (R11 proven) ----------------
__global__ __launch_bounds__(256) void k_lsum(const f16* __restrict__ Qh, const f16* __restrict__ Kf,
                                              float* __restrict__ lpart) {
    int qt = blockIdx.x, bh = blockIdx.y, kc = blockIdx.z;
    int q0 = qt * 64;
    int t = threadIdx.x, lane = t & 63, w = t >> 6;
    const f16* qbase = Qh + ((size_t)bh * 2048 + q0 + w * 16) * 64;
    const f16* kfb = Kf + (size_t)bh * 32 * 4096 + (size_t)lane * 8;

    f16x8 aq[2];
#pragma unroll
    for (int f = 0; f < 2; ++f)
        aq[f] = *(const f16x8*)(qbase + (size_t)(lane & 15) * 64 + f * 32 + (lane >> 4) * 8);
    f32x4 zero = {0.f, 0.f, 0.f, 0.f};

    auto LOADK = [&](f16x8* dst, int kt) {
        const f16* kp = kfb + (size_t)kt * 4096;
#pragma unroll
        for (int f = 0; f < 8; ++f) dst[f] = *(const f16x8*)(kp + f * 512);
    };
    auto QKTS = [&](const f16x8* kf, f32x4* s4) {   // swapped: A=K, B=Q
#pragma unroll
        for (int s = 0; s < 4; ++s) {
            s4[s] = MFMA16(kf[2 * s], aq[0], zero);
            s4[s] = MFMA16(kf[2 * s + 1], aq[1], s4[s]);
        }
    };

    f16x8 ka[8], kb2[8];
    float lsum = 0.f;
    int base = kc * 8;
    LOADK(ka, base);
    for (int i = 0; i < 8; i += 2) {
        f32x4 s4[4];
        LOADK(kb2, base + i + 1);
        QKTS(ka, s4);
#pragma unroll
        for (int s = 0; s < 4; ++s)
#pragma unroll
            for (int r = 0; r < 4; ++r) lsum += fexp2(s4[s][r]);
        LOADK(ka, base + ((i + 2) & 7));
        QKTS(kb2, s4);
#pragma unroll
        for (int s = 0; s < 4; ++s)
#pragma unroll
            for (int r = 0; r < 4; ++r) lsum += fexp2(s4[s][r]);
    }
    lsum += __shfl_xor(lsum, 16, 64);
    lsum += __shfl_xor(lsum, 32, 64);
    float* lp = lpart + (size_t)kc * 49152 + (size_t)bh * 2048 + q0 + w * 16;
    if (lane < 16) lp[lane] = lsum;
}

// ---------------- attention pass 2: 8 waves, kt-split pairs, SOFTWARE-PIPELINED ----------------
// PV lags QK^T by one tile. Per iteration: issue V(kt-1) + LDS reads of the PREVIOUS
// tile's P (double-buffered wave-private Ps) -> QK^T(kt) -> K reload -> srow reads ->
// exp+write Ps[cur] -> stores(kt-1) -> PV(kt-1). The ds_write->ds_read gap becomes a
// full iteration; pa/srow latency hides under QK^T+exp; PV's vbuf wait leaves stores
// outstanding (vmcnt ~12, never drained).
__global__ __launch_bounds__(512, 4) void k_attn(const f16* __restrict__ Qh, const f16* __restrict__ Kf,
                                                 const f16* __restrict__ Vf,
                                                 const float* __restrict__ lpart,
                                                 float* __restrict__ attn, f16* __restrict__ valh) {
    __shared__ __align__(16) float Ps32_all[8][2][16 * 68];
    int orig = blockIdx.x;
    int swz = (orig & 7) * 96 + (orig >> 3);   // 768 blocks, 8 XCDs, bijective
    int bh = swz >> 5, qt = swz & 31;
    int q0 = qt * 64;
    int t = threadIdx.x, lane = t & 63, w = t >> 6;
    int qg = w >> 1, half = w & 1;

    const f16* qbase = Qh + ((size_t)bh * 2048 + q0 + qg * 16) * 64;
    const f16* kfb = Kf + (size_t)bh * 32 * 4096 + (size_t)lane * 8;
    const f16* vfb = Vf + (size_t)bh * 32 * 4096 + (size_t)lane * 8;

    f16x8 aq[2];
#pragma unroll
    for (int f = 0; f < 2; ++f)
        aq[f] = *(const f16x8*)(qbase + (size_t)(lane & 15) * 64 + f * 32 + (lane >> 4) * 8);
    f32x4 zero = {0.f, 0.f, 0.f, 0.f};

    float linv;
    {
        size_t qoff = (size_t)bh * 2048 + q0 + qg * 16 + (lane & 15);
        float s = 0.f;
#pragma unroll
        for (int kc = 0; kc < 4; ++kc) s += lpart[(size_t)kc * 49152 + qoff];
        linv = 1.0f / s;
    }

    f16x8 ka[8], vbuf[8];
    auto LOADK = [&](int kt) {
        const f16* kp = kfb + (size_t)kt * 4096;
#pragma unroll
        for (int f = 0; f < 8; ++f) ka[f] = *(const f16x8*)(kp + f * 512);
    };
    auto LOADV = [&](int kt) {
        const f16* vp = vfb + (size_t)kt * 4096;
#pragma unroll
        for (int f = 0; f < 8; ++f) vbuf[f] = *(const f16x8*)(vp + f * 512);
    };
    auto QKTS = [&](f32x4* s4) {   // swapped: A=K, B=Q; lane holds S^T[k][q=lane&15]
#pragma unroll
        for (int s = 0; s < 4; ++s) {
            s4[s] = MFMA16(ka[2 * s], aq[0], zero);
            s4[s] = MFMA16(ka[2 * s + 1], aq[1], s4[s]);
        }
    };
    auto WRITEPS = [&](float* Ps, f32x4* s4) {
#pragma unroll
        for (int s = 0; s < 4; ++s) {
            f32x4 pv;
#pragma unroll
            for (int r = 0; r < 4; ++r) pv[r] = fexp2(s4[s][r]) * linv;
            *(f32x4*)(Ps + (lane & 15) * 68 + s * 16 + (lane >> 4) * 4) = pv;
        }
    };

    f32x4 accv[4];
#pragma unroll
    for (int j = 0; j < 4; ++j) accv[j] = zero;
    float* PsW = Ps32_all[w][0];
    float* PsR = Ps32_all[w][1];
    float* attn_base = attn + ((size_t)bh * 2048 + q0 + qg * 16) * 2048;

    int ktbase = half * 16;
    LOADK(ktbase);
    {   // prologue: QK^T(ktbase) only
        f32x4 s4[4];
        QKTS(s4);
        LOADK(ktbase + 1);
        WRITEPS(PsW, s4);
        float* tmp = PsW; PsW = PsR; PsR = tmp;
    }
    for (int i = 1; i < 16; ++i) {
        int kt = ktbase + i, ktp = kt - 1;
        // 1) V for the lagging PV tile
        LOADV(ktp);
        // 2) pa reads from previous tile's P (latency hides under QK^T+exp)
        const float* pr0 = PsR + (lane & 15) * 68 + (lane >> 4) * 8;
        f32x4 plo0 = *(const f32x4*)(pr0);
        f32x4 phi0 = *(const f32x4*)(pr0 + 4);
        f32x4 plo1 = *(const f32x4*)(pr0 + 32);
        f32x4 phi1 = *(const f32x4*)(pr0 + 36);
        // 3) QK^T current (vmcnt wait for ka leaves stores outstanding)
        f32x4 s4[4];
        QKTS(s4);
        // 4) K reload for next tile
        LOADK((kt + 1) & 31);
        // 5) store-row reads (feed step 7)
        f32x4 srow[4];
#pragma unroll
        for (int ii = 0; ii < 4; ++ii)
            srow[ii] = *(const f32x4*)(PsR + (ii * 4 + (lane >> 4)) * 68 + (lane & 15) * 4);
        // 6) exp + write current P tile
        WRITEPS(PsW, s4);
        // 7) coalesced attention stores for ktp (256B runs)
        float* ab = attn_base + ktp * 64;
#pragma unroll
        for (int ii = 0; ii < 4; ++ii)
            *(f32x4*)(ab + (size_t)(ii * 4 + (lane >> 4)) * 2048 + (lane & 15) * 4) = srow[ii];
        // 8) PV for ktp
        f16x8 pa0 = {(f16)plo0[0], (f16)plo0[1], (f16)plo0[2], (f16)plo0[3],
                     (f16)phi0[0], (f16)phi0[1], (f16)phi0[2], (f16)phi0[3]};
        f16x8 pa1 = {(f16)plo1[0], (f16)plo1[1], (f16)plo1[2], (f16)plo1[3],
                     (f16)phi1[0], (f16)phi1[1], (f16)phi1[2], (f16)phi1[3]};
#pragma unroll
        for (int jd = 0; jd < 4; ++jd) {
            accv[jd] = MFMA16(pa0, vbuf[2 * jd], accv[jd]);
            accv[jd] = MFMA16(pa1, vbuf[2 * jd + 1], accv[jd]);
        }
        float* tmp = PsW; PsW = PsR; PsR = tmp;
    }
    {   // epilogue: PV + stores for ktbase+15
        int ktp = ktbase + 15;
        LOADV(ktp);
        const float* pr0 = PsR + (lane & 15) * 68 + (lane >> 4) * 8;
        f32x4 plo0 = *(const f32x4*)(pr0);
        f32x4 phi0 = *(const f32x4*)(pr0 + 4);
        f32x4 plo1 = *(const f32x4*)(pr0 + 32);
        f32x4 phi1 = *(const f32x4*)(pr0 + 36);
        f32x4 srow[4];
#pragma unroll
        for (int ii = 0; ii < 4; ++ii)
            srow[ii] = *(const f32x4*)(PsR + (ii * 4 + (lane >> 4)) * 68 + (lane & 15) * 4);
        float* ab = attn_base + ktp * 64;
#pragma unroll
        for (int ii = 0; ii < 4; ++ii)
            *(f32x4*)(ab + (size_t)(ii * 4 + (lane >> 4)) * 2048 + (lane & 15) * 4) = srow[ii];
        f16x8 pa0 = {(f16)plo0[0], (f16)plo0[1], (f16)plo0[2], (f16)plo0[3],
                     (f16)phi0[0], (f16)phi0[1], (f16)phi0[2], (f16)phi0[3]};
        f16x8 pa1 = {(f16)plo1[0], (f16)plo1[1], (f16)plo1[2], (f16)plo1[3],
                     (f16)phi1[0], (f16)phi1[1], (f16)phi1[2], (f16)phi1[3]};
#pragma unroll
        for (int jd = 0; jd < 4; ++jd) {
            accv[jd] = MFMA16(pa0, vbuf[2 * jd], accv[jd]);
            accv[jd] = MFMA16(pa1, vbuf[2 * jd + 1], accv[jd]);
        }
    }

    // combine PV halves through LDS (buffer 0), then wave 0 of each pair writes valh
    float* Pc = Ps32_all[w][0];
    if (half) {
#pragma unroll
        for (int j = 0; j < 4; ++j)
#pragma unroll
            for (int r = 0; r < 4; ++r)
                Pc[((lane >> 4) * 4 + r) * 68 + j * 16 + (lane & 15)] = accv[j][r];
    }
    __syncthreads();
    if (!half) {
        const float* Pp = Ps32_all[w + 1][0];
        int b = bh / 12, h = bh - b * 12;
#pragma unroll
        for (int j = 0; j < 4; ++j) {
#pragma unroll
            for (int r = 0; r < 4; ++r) {
                float v = accv[j][r] + Pp[((lane >> 4) * 4 + r) * 68 + j * 16 + (lane & 15)];
                int rowg = b * 2048 + q0 + qg * 16 + (lane >> 4) * 4 + r;
                int col = h * 64 + j * 16 + (lane & 15);
                valh[(size_t)rowg * 768 + col] = (f16)v;
            }
        }
    }
}

extern "C" void kernel_launch(void* const* d_in, const int* in_sizes, int n_in,
                              void* d_out, int out_size, void* d_ws, size_t ws_size,
                              hipStream_t stream) {
    const float* x = (const float*)d_in[0];
    const float* wqkv = (const float*)d_in[1];
    const float* bqkv = (const float*)d_in[2];
    const float* wo = (const float*)d_in[3];
    const float* bo = (const float*)d_in[4];

    float* out_o = (float*)d_out;                          // [2,2048,768] fp32
    float* out_attn = out_o + (size_t)2 * 2048 * 768;      // [2,12,2048,2048] fp32

    f16* ws = (f16*)d_ws;
    f16* xh = ws;                       // 3,145,728 f16
    f16* wqkv_t = xh + 3145728;         // [2304][768]
    f16* wo_t = wqkv_t + 1769472;       // [768][768]
    f16* Qh = wo_t + 589824;            // [bh][t][64], pre-scaled
    f16* Kf = Qh + 3145728;             // fragment-linear K
    f16* Vf = Kf + 3145728;             // fragment-linear V
    f16* valh = Vf + 3145728;           // [4096][768]
    float* lpart = (float*)(valh + 3145728);  // [4][24*2048] f32 split-k partials

    k_convert_x<<<3072, 256, 0, stream>>>(x, xh, 786432);
    k_transpose<<<dim3(36, 12), 256, 0, stream>>>(wqkv, wqkv_t, 768, 2304);
    k_transpose<<<dim3(12, 12), 256, 0, stream>>>(wo, wo_t, 768, 768);
    k_qkv_gemm<<<dim3(32, 18), 256, 0, stream>>>(xh, wqkv_t, bqkv, Qh, Kf, Vf);
    k_lsum<<<dim3(32, 24, 4), 256, 0, stream>>>(Qh, Kf, lpart);
    k_attn<<<768, 512, 0, stream>>>(Qh, Kf, Vf, lpart, out_attn, valh);
    k_o_gemm<<<dim3(32, 6), 256, 0, stream>>>(valh, wo_t, bo, out_o);
}

// Round 14
// 202.581 us; speedup vs baseline: 1.0670x; 1.0670x over previous
//
#include <hip/hip_runtime.h>
#include <hip/hip_bf16.h>
#include <hip/hip_fp16.h>

typedef _Float16 f16;
typedef _Float16 f16x4 __attribute__((ext_vector_type(4)));
typedef _Float16 f16x8 __attribute__((ext_vector_type(8)));
typedef float f32x4 __attribute__((ext_vector_type(4)));

#define MFMA16(a, b, c) __builtin_amdgcn_mfma_f32_16x16x32_f16(a, b, c, 0, 0, 0)

__device__ __forceinline__ float fexp2(float x) {
#if __has_builtin(__builtin_amdgcn_exp2f)
    return __builtin_amdgcn_exp2f(x);
#else
    return exp2f(x);
#endif
}

typedef __attribute__((address_space(1))) const void gconst_t;
typedef __attribute__((address_space(3))) void lds_t;
__device__ __forceinline__ void gload16(const f16* g, f16* l) {
    __builtin_amdgcn_global_load_lds((gconst_t*)g, (lds_t*)l, 16, 0, 0);
}

// ---------------- prep: f32 -> f16 convert ----------------
__global__ void k_convert_x(const float* __restrict__ in, f16* __restrict__ out, int n4) {
    int i = blockIdx.x * blockDim.x + threadIdx.x;
    if (i >= n4) return;
    float4 v = ((const float4*)in)[i];
    f16x4 o = {(f16)v.x, (f16)v.y, (f16)v.z, (f16)v.w};
    ((f16x4*)out)[i] = o;
}

// ---------------- prep: transpose f32[K][N] -> f16[N][K] ----------------
__global__ __launch_bounds__(256) void k_transpose(const float* __restrict__ in,
                                                   f16* __restrict__ out, int K, int N) {
    __shared__ f16 tile[64][72];
    int n0 = blockIdx.x * 64, k0 = blockIdx.y * 64;
    int t = threadIdx.x;
    int r = t >> 2, cb = (t & 3) * 16;
    const float* src = in + (size_t)(k0 + r) * N + n0 + cb;
#pragma unroll
    for (int j = 0; j < 4; ++j) {
        float4 v = ((const float4*)src)[j];
        tile[r][cb + 4 * j + 0] = (f16)v.x;
        tile[r][cb + 4 * j + 1] = (f16)v.y;
        tile[r][cb + 4 * j + 2] = (f16)v.z;
        tile[r][cb + 4 * j + 3] = (f16)v.w;
    }
    __syncthreads();
    int nl = t >> 2, kb = (t & 3) * 16;
    f16* dst = out + (size_t)(n0 + nl) * K + k0 + kb;
#pragma unroll
    for (int j = 0; j < 2; ++j) {
        f16x8 o;
#pragma unroll
        for (int e = 0; e < 8; ++e) o[e] = tile[kb + 8 * j + e][nl];
        *(f16x8*)(dst + 8 * j) = o;
    }
}

// ---------------- shared GEMM core (R8): global_load_lds + XOR-swizzled LDS ----------------
__device__ __forceinline__ void gemm_core(const f16* __restrict__ A, const f16* __restrict__ Bt,
                                          int m0, int n0, int lane, int w, int wr, int wc,
                                          f16* As, f16* Bs, f32x4 acc[4][4]) {
    int prow = lane >> 2, pc = lane & 3;
    int lrow = prow ^ ((prow >> 2) & 1);
    int lcol = (pc ^ (lrow & 3)) * 8;
    int rsw = (lane & 7) << 3;
    for (int kt = 0; kt < 24; ++kt) {
        const f16* ab = A + (size_t)(m0 + w * 32 + lrow) * 768 + kt * 32 + lcol;
        const f16* bb = Bt + (size_t)(n0 + w * 32 + lrow) * 768 + kt * 32 + lcol;
        gload16(ab, As + (w * 32) * 32);
        gload16(ab + (size_t)16 * 768, As + (w * 32 + 16) * 32);
        gload16(bb, Bs + (w * 32) * 32);
        gload16(bb + (size_t)16 * 768, Bs + (w * 32 + 16) * 32);
        __syncthreads();
        f16x8 a[4], b[4];
#pragma unroll
        for (int i = 0; i < 4; ++i) {
            int idx = (wr * 64 + i * 16 + (lane & 15)) * 32 + (lane >> 4) * 8;
            a[i] = *(const f16x8*)(As + (idx ^ rsw));
        }
#pragma unroll
        for (int j = 0; j < 4; ++j) {
            int idx = (wc * 64 + j * 16 + (lane & 15)) * 32 + (lane >> 4) * 8;
            b[j] = *(const f16x8*)(Bs + (idx ^ rsw));
        }
#pragma unroll
        for (int i = 0; i < 4; ++i)
#pragma unroll
            for (int j = 0; j < 4; ++j) acc[i][j] = MFMA16(a[i], b[j], acc[i][j]);
        __syncthreads();
    }
}

// ---------------- QKV GEMM -> Qh (row layout), Kf/Vf (fragment-linear) ----------------
__global__ __launch_bounds__(256) void k_qkv_gemm(const f16* __restrict__ A, const f16* __restrict__ Bt,
                                                  const float* __restrict__ bias,
                                                  f16* __restrict__ Qh, f16* __restrict__ Kf,
                                                  f16* __restrict__ Vf) {
    __shared__ __align__(16) f16 As[128 * 32];
    __shared__ __align__(16) f16 Bs[128 * 32];
    int m0 = blockIdx.x * 128, n0 = blockIdx.y * 128;
    int t = threadIdx.x, lane = t & 63, w = t >> 6;
    int wr = w >> 1, wc = w & 1;
    f32x4 zero = {0.f, 0.f, 0.f, 0.f};
    f32x4 acc[4][4];
#pragma unroll
    for (int i = 0; i < 4; ++i)
#pragma unroll
        for (int j = 0; j < 4; ++j) acc[i][j] = zero;

    gemm_core(A, Bt, m0, n0, lane, w, wr, wc, As, Bs, acc);

    const float QSCALE = 0.18033688011112042f;  // 0.125 * log2(e)
#pragma unroll
    for (int j = 0; j < 4; ++j) {
        int n = n0 + wc * 64 + j * 16 + (lane & 15);
        int which = n / 768;
        int rem = n - which * 768;
        int h = rem >> 6, d = rem & 63;
        float bv = bias[n];
#pragma unroll
        for (int i = 0; i < 4; ++i) {
            int m = m0 + wr * 64 + i * 16 + ((lane >> 4) << 2);
            int bb = m >> 11, tt = m & 2047;
            int bh = bb * 12 + h;
            if (which == 2) {
                int kt = tt >> 6;
                int half = (tt & 63) >> 5, hi = (tt & 31) >> 3, e0 = tt & 7;
                int jd = d >> 4, lo = d & 15;
                size_t addr = (((size_t)bh * 32 + kt) * 8 + jd * 2 + half) * 512 +
                              (size_t)(hi * 16 + lo) * 8 + e0;
                f16x4 pk;
#pragma unroll
                for (int r = 0; r < 4; ++r) pk[r] = (f16)(acc[i][j][r] + bv);
                *(f16x4*)(Vf + addr) = pk;
            } else if (which == 0) {
#pragma unroll
                for (int r = 0; r < 4; ++r)
                    Qh[((size_t)bh * 2048 + tt + r) * 64 + d] = (f16)((acc[i][j][r] + bv) * QSCALE);
            } else {
                int half = d >> 5, hi = (d & 31) >> 3, e = d & 7;
#pragma unroll
                for (int r = 0; r < 4; ++r) {
                    int tr = tt + r;
                    int kt = tr >> 6, row = tr & 63;
                    int s = row >> 4, lo = row & 15;
                    size_t addr = (((size_t)bh * 32 + kt) * 8 + s * 2 + half) * 512 +
                                  (size_t)(hi * 16 + lo) * 8 + e;
                    Kf[addr] = (f16)(acc[i][j][r] + bv);
                }
            }
        }
    }
}

// ---------------- O GEMM ----------------
__global__ __launch_bounds__(256) void k_o_gemm(const f16* __restrict__ A, const f16* __restrict__ Bt,
                                                const float* __restrict__ bias,
                                                float* __restrict__ out) {
    __shared__ __align__(16) f16 As[128 * 32];
    __shared__ __align__(16) f16 Bs[128 * 32];
    int m0 = blockIdx.x * 128, n0 = blockIdx.y * 128;
    int t = threadIdx.x, lane = t & 63, w = t >> 6;
    int wr = w >> 1, wc = w & 1;
    f32x4 zero = {0.f, 0.f, 0.f, 0.f};
    f32x4 acc[4][4];
#pragma unroll
    for (int i = 0; i < 4; ++i)
#pragma unroll
        for (int j = 0; j < 4; ++j) acc[i][j] = zero;

    gemm_core(A, Bt, m0, n0, lane, w, wr, wc, As, Bs, acc);

#pragma unroll
    for (int j = 0; j < 4; ++j) {
        int n = n0 + wc * 64 + j * 16 + (lane & 15);
        float bv = bias[n];
#pragma unroll
        for (int i = 0; i < 4; ++i) {
            int m = m0 + wr * 64 + i * 16 + ((lane >> 4) << 2);
#pragma unroll
            for (int r = 0; r < 4; ++r) out[(size_t)(m + r) * 768 + n] = acc[i][j][r] + bv;
        }
    }
}

// ---------------- lsum: split-k partial row-sums, swapped QK^T (R11 proven) ----------------
__global__ __launch_bounds__(256) void k_lsum(const f16* __restrict__ Qh, const f16* __restrict__ Kf,
                                              float* __restrict__ lpart) {
    int qt = blockIdx.x, bh = blockIdx.y, kc = blockIdx.z;
    int q0 = qt * 64;
    int t = threadIdx.x, lane = t & 63, w = t >> 6;
    const f16* qbase = Qh + ((size_t)bh * 2048 + q0 + w * 16) * 64;
    const f16* kfb = Kf + (size_t)bh * 32 * 4096 + (size_t)lane * 8;

    f16x8 aq[2];
#pragma unroll
    for (int f = 0; f < 2; ++f)
        aq[f] = *(const f16x8*)(qbase + (size_t)(lane & 15) * 64 + f * 32 + (lane >> 4) * 8);
    f32x4 zero = {0.f, 0.f, 0.f, 0.f};

    auto LOADK = [&](f16x8* dst, int kt) {
        const f16* kp = kfb + (size_t)kt * 4096;
#pragma unroll
        for (int f = 0; f < 8; ++f) dst[f] = *(const f16x8*)(kp + f * 512);
    };
    auto QKTS = [&](const f16x8* kf, f32x4* s4) {   // swapped: A=K, B=Q
        __builtin_amdgcn_s_setprio(1);
#pragma unroll
        for (int s = 0; s < 4; ++s) {
            s4[s] = MFMA16(kf[2 * s], aq[0], zero);
            s4[s] = MFMA16(kf[2 * s + 1], aq[1], s4[s]);
        }
        __builtin_amdgcn_s_setprio(0);
    };

    f16x8 ka[8], kb2[8];
    float lsum = 0.f;
    int base = kc * 8;
    LOADK(ka, base);
    for (int i = 0; i < 8; i += 2) {
        f32x4 s4[4];
        LOADK(kb2, base + i + 1);
        QKTS(ka, s4);
#pragma unroll
        for (int s = 0; s < 4; ++s)
#pragma unroll
            for (int r = 0; r < 4; ++r) lsum += fexp2(s4[s][r]);
        LOADK(ka, base + ((i + 2) & 7));
        QKTS(kb2, s4);
#pragma unroll
        for (int s = 0; s < 4; ++s)
#pragma unroll
            for (int r = 0; r < 4; ++r) lsum += fexp2(s4[s][r]);
    }
    lsum += __shfl_xor(lsum, 16, 64);
    lsum += __shfl_xor(lsum, 32, 64);
    float* lp = lpart + (size_t)kc * 49152 + (size_t)bh * 2048 + q0 + w * 16;
    if (lane < 16) lp[lane] = lsum;
}

// ---------------- attention pass 2 (R12 structure + setprio): 8 waves, kt-split pairs ----------------
// grid 768 x 512 threads. Waves (2qg, 2qg+1) both own q-group qg (16 rows); half 0 streams
// kt 0..15, half 1 streams kt 16..31. 2 blocks/CU resident (VGPR<=128) -> 16 waves/CU.
// K single-buffered (reloaded after QK^T consumes it); V loaded first each iteration so
// load-waits never force the 400 MB store stream to retire. s_setprio(1) wraps the MFMA
// clusters (T5): barrier-free waves sit at different phases, so MFMA-ready waves win
// issue arbitration over load-issuing waves. PV halves combined through LDS at the end.
__global__ __launch_bounds__(512, 4) void k_attn(const f16* __restrict__ Qh, const f16* __restrict__ Kf,
                                                 const f16* __restrict__ Vf,
                                                 const float* __restrict__ lpart,
                                                 float* __restrict__ attn, f16* __restrict__ valh) {
    __shared__ __align__(16) float Ps32_all[8][16 * 68];
    int orig = blockIdx.x;
    int swz = (orig & 7) * 96 + (orig >> 3);   // 768 blocks, 8 XCDs, bijective
    int bh = swz >> 5, qt = swz & 31;
    int q0 = qt * 64;
    int t = threadIdx.x, lane = t & 63, w = t >> 6;
    int qg = w >> 1, half = w & 1;

    const f16* qbase = Qh + ((size_t)bh * 2048 + q0 + qg * 16) * 64;
    const f16* kfb = Kf + (size_t)bh * 32 * 4096 + (size_t)lane * 8;
    const f16* vfb = Vf + (size_t)bh * 32 * 4096 + (size_t)lane * 8;

    f16x8 aq[2];
#pragma unroll
    for (int f = 0; f < 2; ++f)
        aq[f] = *(const f16x8*)(qbase + (size_t)(lane & 15) * 64 + f * 32 + (lane >> 4) * 8);
    f32x4 zero = {0.f, 0.f, 0.f, 0.f};

    // scalar linv: this lane's q-row = q0 + qg*16 + (lane&15)
    float linv;
    {
        size_t qoff = (size_t)bh * 2048 + q0 + qg * 16 + (lane & 15);
        float s = 0.f;
#pragma unroll
        for (int kc = 0; kc < 4; ++kc) s += lpart[(size_t)kc * 49152 + qoff];
        linv = 1.0f / s;
    }

    auto LOADK = [&](f16x8* dst, int kt) {
        const f16* kp = kfb + (size_t)kt * 4096;
#pragma unroll
        for (int f = 0; f < 8; ++f) dst[f] = *(const f16x8*)(kp + f * 512);
    };

    f32x4 accv[4];
#pragma unroll
    for (int j = 0; j < 4; ++j) accv[j] = zero;
    float* Ps = Ps32_all[w];   // wave-private 16 x 68 f32, [q][k]
    float* attn_base = attn + ((size_t)bh * 2048 + q0 + qg * 16) * 2048;
    f16x8 ka[8], vbuf[8];

    int ktbase = half * 16;
    LOADK(ka, ktbase);
    for (int kt = ktbase; kt < ktbase + 16; ++kt) {
        // 1) V loads first (oldest in-flight)
        {
            const f16* vp = vfb + (size_t)kt * 4096;
#pragma unroll
            for (int f = 0; f < 8; ++f) vbuf[f] = *(const f16x8*)(vp + f * 512);
        }
        // 2) swapped QK^T on current K: lane holds S[k=s*16+(lane>>4)*4+r][q=lane&15]
        f32x4 s4[4];
        __builtin_amdgcn_s_setprio(1);
#pragma unroll
        for (int s = 0; s < 4; ++s) {
            s4[s] = MFMA16(ka[2 * s], aq[0], zero);
            s4[s] = MFMA16(ka[2 * s + 1], aq[1], s4[s]);
        }
        __builtin_amdgcn_s_setprio(0);
        // 3) reload K for next iteration (WAR on ka: issues after MFMAs consume it)
        LOADK(ka, (kt + 1) & 31);
        // 4) softmax -> Ps[q][k]: 4x ds_write_b128
#pragma unroll
        for (int s = 0; s < 4; ++s) {
            f32x4 pv;
#pragma unroll
            for (int r = 0; r < 4; ++r) pv[r] = fexp2(s4[s][r]) * linv;
            *(f32x4*)(Ps + (lane & 15) * 68 + s * 16 + (lane >> 4) * 4) = pv;
        }
        // 5) PV A-fragment (f16) from the tile
        f16x8 pa[2];
#pragma unroll
        for (int hh = 0; hh < 2; ++hh) {
            const float* pr = Ps + (lane & 15) * 68 + hh * 32 + (lane >> 4) * 8;
            f32x4 lo = *(const f32x4*)(pr);
            f32x4 hi = *(const f32x4*)(pr + 4);
            f16x8 pf = {(f16)lo[0], (f16)lo[1], (f16)lo[2], (f16)lo[3],
                        (f16)hi[0], (f16)hi[1], (f16)hi[2], (f16)hi[3]};
            pa[hh] = pf;
        }
        // 6) coalesced attention stores: 4x dwordx4 (256B runs per 16-lane group)
        float* ab = attn_base + kt * 64;
#pragma unroll
        for (int i = 0; i < 4; ++i) {
            int row = i * 4 + (lane >> 4);
            int col = (lane & 15) * 4;
            f32x4 v = *(const f32x4*)(Ps + row * 68 + col);
            *(f32x4*)(ab + (size_t)row * 2048 + col) = v;
        }
        // 7) PV MFMA (waits vbuf; K reload + stores are younger, stay outstanding)
        __builtin_amdgcn_s_setprio(1);
#pragma unroll
        for (int jd = 0; jd < 4; ++jd) {
            accv[jd] = MFMA16(pa[0], vbuf[2 * jd], accv[jd]);
            accv[jd] = MFMA16(pa[1], vbuf[2 * jd + 1], accv[jd]);
        }
        __builtin_amdgcn_s_setprio(0);
    }

    // combine PV halves through LDS, then wave 0 of each pair writes valh
    if (half) {
#pragma unroll
        for (int j = 0; j < 4; ++j)
#pragma unroll
            for (int r = 0; r < 4; ++r)
                Ps[((lane >> 4) * 4 + r) * 68 + j * 16 + (lane & 15)] = accv[j][r];
    }
    __syncthreads();
    if (!half) {
        const float* Pp = Ps32_all[w + 1];
        int b = bh / 12, h = bh - b * 12;
#pragma unroll
        for (int j = 0; j < 4; ++j) {
#pragma unroll
            for (int r = 0; r < 4; ++r) {
                float v = accv[j][r] + Pp[((lane >> 4) * 4 + r) * 68 + j * 16 + (lane & 15)];
                int rowg = b * 2048 + q0 + qg * 16 + (lane >> 4) * 4 + r;
                int col = h * 64 + j * 16 + (lane & 15);
                valh[(size_t)rowg * 768 + col] = (f16)v;
            }
        }
    }
}

extern "C" void kernel_launch(void* const* d_in, const int* in_sizes, int n_in,
                              void* d_out, int out_size, void* d_ws, size_t ws_size,
                              hipStream_t stream) {
    const float* x = (const float*)d_in[0];
    const float* wqkv = (const float*)d_in[1];
    const float* bqkv = (const float*)d_in[2];
    const float* wo = (const float*)d_in[3];
    const float* bo = (const float*)d_in[4];

    float* out_o = (float*)d_out;                          // [2,2048,768] fp32
    float* out_attn = out_o + (size_t)2 * 2048 * 768;      // [2,12,2048,2048] fp32

    f16* ws = (f16*)d_ws;
    f16* xh = ws;                       // 3,145,728 f16
    f16* wqkv_t = xh + 3145728;         // [2304][768]
    f16* wo_t = wqkv_t + 1769472;       // [768][768]
    f16* Qh = wo_t + 589824;            // [bh][t][64], pre-scaled
    f16* Kf = Qh + 3145728;             // fragment-linear K
    f16* Vf = Kf + 3145728;             // fragment-linear V
    f16* valh = Vf + 3145728;           // [4096][768]
    float* lpart = (float*)(valh + 3145728);  // [4][24*2048] f32 split-k partials

    k_convert_x<<<3072, 256, 0, stream>>>(x, xh, 786432);
    k_transpose<<<dim3(36, 12), 256, 0, stream>>>(wqkv, wqkv_t, 768, 2304);
    k_transpose<<<dim3(12, 12), 256, 0, stream>>>(wo, wo_t, 768, 768);
    k_qkv_gemm<<<dim3(32, 18), 256, 0, stream>>>(xh, wqkv_t, bqkv, Qh, Kf, Vf);
    k_lsum<<<dim3(32, 24, 4), 256, 0, stream>>>(Qh, Kf, lpart);
    k_attn<<<768, 512, 0, stream>>>(Qh, Kf, Vf, lpart, out_attn, valh);
    k_o_gemm<<<dim3(32, 6), 256, 0, stream>>>(valh, wo_t, bo, out_o);
}

// Round 15
// 188.408 us; speedup vs baseline: 1.1472x; 1.0752x over previous
//
#include <hip/hip_runtime.h>
#include <hip/hip_bf16.h>
#include <hip/hip_fp16.h>

typedef _Float16 f16;
typedef _Float16 f16x4 __attribute__((ext_vector_type(4)));
typedef _Float16 f16x8 __attribute__((ext_vector_type(8)));
typedef float f32x4 __attribute__((ext_vector_type(4)));

#define MFMA16(a, b, c) __builtin_amdgcn_mfma_f32_16x16x32_f16(a, b, c, 0, 0, 0)

__device__ __forceinline__ float fexp2(float x) {
#if __has_builtin(__builtin_amdgcn_exp2f)
    return __builtin_amdgcn_exp2f(x);
#else
    return exp2f(x);
#endif
}

typedef __attribute__((address_space(1))) const void gconst_t;
typedef __attribute__((address_space(3))) void lds_t;
__device__ __forceinline__ void gload16(const f16* g, f16* l) {
    __builtin_amdgcn_global_load_lds((gconst_t*)g, (lds_t*)l, 16, 0, 0);
}

// ---------------- fused prep: convert x + transpose wqkv + transpose wo ----------------
__device__ __forceinline__ void transpose_body(const float* __restrict__ in, f16* __restrict__ out,
                                               int K, int N, int n0, int k0, int t,
                                               f16 (*tile)[72]) {
    int r = t >> 2, cb = (t & 3) * 16;
    const float* src = in + (size_t)(k0 + r) * N + n0 + cb;
#pragma unroll
    for (int j = 0; j < 4; ++j) {
        float4 v = ((const float4*)src)[j];
        tile[r][cb + 4 * j + 0] = (f16)v.x;
        tile[r][cb + 4 * j + 1] = (f16)v.y;
        tile[r][cb + 4 * j + 2] = (f16)v.z;
        tile[r][cb + 4 * j + 3] = (f16)v.w;
    }
    __syncthreads();
    int nl = t >> 2, kb = (t & 3) * 16;
    f16* dst = out + (size_t)(n0 + nl) * K + k0 + kb;
#pragma unroll
    for (int j = 0; j < 2; ++j) {
        f16x8 o;
#pragma unroll
        for (int e = 0; e < 8; ++e) o[e] = tile[kb + 8 * j + e][nl];
        *(f16x8*)(dst + 8 * j) = o;
    }
}

__global__ __launch_bounds__(256) void k_prep(const float* __restrict__ x,
                                              const float* __restrict__ wqkv,
                                              const float* __restrict__ wo,
                                              f16* __restrict__ xh, f16* __restrict__ wqkv_t,
                                              f16* __restrict__ wo_t) {
    __shared__ f16 tile[64][72];
    int bid = blockIdx.x, t = threadIdx.x;
    if (bid < 3072) {
        int i = bid * 256 + t;   // n4 = 786432, grid section exactly covers it
        float4 v = ((const float4*)x)[i];
        f16x4 o = {(f16)v.x, (f16)v.y, (f16)v.z, (f16)v.w};
        ((f16x4*)xh)[i] = o;
    } else if (bid < 3504) {
        int idx = bid - 3072;    // 432 = 36 x 12
        transpose_body(wqkv, wqkv_t, 768, 2304, (idx % 36) * 64, (idx / 36) * 64, t, tile);
    } else {
        int idx = bid - 3504;    // 144 = 12 x 12
        transpose_body(wo, wo_t, 768, 768, (idx % 12) * 64, (idx / 12) * 64, t, tile);
    }
}

// ---------------- shared GEMM core (R8): global_load_lds + XOR-swizzled LDS ----------------
__device__ __forceinline__ void gemm_core(const f16* __restrict__ A, const f16* __restrict__ Bt,
                                          int m0, int n0, int lane, int w, int wr, int wc,
                                          f16* As, f16* Bs, f32x4 acc[4][4]) {
    int prow = lane >> 2, pc = lane & 3;
    int lrow = prow ^ ((prow >> 2) & 1);
    int lcol = (pc ^ (lrow & 3)) * 8;
    int rsw = (lane & 7) << 3;
    for (int kt = 0; kt < 24; ++kt) {
        const f16* ab = A + (size_t)(m0 + w * 32 + lrow) * 768 + kt * 32 + lcol;
        const f16* bb = Bt + (size_t)(n0 + w * 32 + lrow) * 768 + kt * 32 + lcol;
        gload16(ab, As + (w * 32) * 32);
        gload16(ab + (size_t)16 * 768, As + (w * 32 + 16) * 32);
        gload16(bb, Bs + (w * 32) * 32);
        gload16(bb + (size_t)16 * 768, Bs + (w * 32 + 16) * 32);
        __syncthreads();
        f16x8 a[4], b[4];
#pragma unroll
        for (int i = 0; i < 4; ++i) {
            int idx = (wr * 64 + i * 16 + (lane & 15)) * 32 + (lane >> 4) * 8;
            a[i] = *(const f16x8*)(As + (idx ^ rsw));
        }
#pragma unroll
        for (int j = 0; j < 4; ++j) {
            int idx = (wc * 64 + j * 16 + (lane & 15)) * 32 + (lane >> 4) * 8;
            b[j] = *(const f16x8*)(Bs + (idx ^ rsw));
        }
#pragma unroll
        for (int i = 0; i < 4; ++i)
#pragma unroll
            for (int j = 0; j < 4; ++j) acc[i][j] = MFMA16(a[i], b[j], acc[i][j]);
        __syncthreads();
    }
}

// ---------------- QKV GEMM -> Qh (row layout), Kf/Vf (fragment-linear) ----------------
__global__ __launch_bounds__(256) void k_qkv_gemm(const f16* __restrict__ A, const f16* __restrict__ Bt,
                                                  const float* __restrict__ bias,
                                                  f16* __restrict__ Qh, f16* __restrict__ Kf,
                                                  f16* __restrict__ Vf) {
    __shared__ __align__(16) f16 As[128 * 32];
    __shared__ __align__(16) f16 Bs[128 * 32];
    int m0 = blockIdx.x * 128, n0 = blockIdx.y * 128;
    int t = threadIdx.x, lane = t & 63, w = t >> 6;
    int wr = w >> 1, wc = w & 1;
    f32x4 zero = {0.f, 0.f, 0.f, 0.f};
    f32x4 acc[4][4];
#pragma unroll
    for (int i = 0; i < 4; ++i)
#pragma unroll
        for (int j = 0; j < 4; ++j) acc[i][j] = zero;

    gemm_core(A, Bt, m0, n0, lane, w, wr, wc, As, Bs, acc);

    const float QSCALE = 0.18033688011112042f;  // 0.125 * log2(e)
#pragma unroll
    for (int j = 0; j < 4; ++j) {
        int n = n0 + wc * 64 + j * 16 + (lane & 15);
        int which = n / 768;
        int rem = n - which * 768;
        int h = rem >> 6, d = rem & 63;
        float bv = bias[n];
#pragma unroll
        for (int i = 0; i < 4; ++i) {
            int m = m0 + wr * 64 + i * 16 + ((lane >> 4) << 2);
            int bb = m >> 11, tt = m & 2047;
            int bh = bb * 12 + h;
            if (which == 2) {
                int kt = tt >> 6;
                int half = (tt & 63) >> 5, hi = (tt & 31) >> 3, e0 = tt & 7;
                int jd = d >> 4, lo = d & 15;
                size_t addr = (((size_t)bh * 32 + kt) * 8 + jd * 2 + half) * 512 +
                              (size_t)(hi * 16 + lo) * 8 + e0;
                f16x4 pk;
#pragma unroll
                for (int r = 0; r < 4; ++r) pk[r] = (f16)(acc[i][j][r] + bv);
                *(f16x4*)(Vf + addr) = pk;
            } else if (which == 0) {
#pragma unroll
                for (int r = 0; r < 4; ++r)
                    Qh[((size_t)bh * 2048 + tt + r) * 64 + d] = (f16)((acc[i][j][r] + bv) * QSCALE);
            } else {
                int half = d >> 5, hi = (d & 31) >> 3, e = d & 7;
#pragma unroll
                for (int r = 0; r < 4; ++r) {
                    int tr = tt + r;
                    int kt = tr >> 6, row = tr & 63;
                    int s = row >> 4, lo = row & 15;
                    size_t addr = (((size_t)bh * 32 + kt) * 8 + s * 2 + half) * 512 +
                                  (size_t)(hi * 16 + lo) * 8 + e;
                    Kf[addr] = (f16)(acc[i][j][r] + bv);
                }
            }
        }
    }
}

// ---------------- O GEMM ----------------
__global__ __launch_bounds__(256) void k_o_gemm(const f16* __restrict__ A, const f16* __restrict__ Bt,
                                                const float* __restrict__ bias,
                                                float* __restrict__ out) {
    __shared__ __align__(16) f16 As[128 * 32];
    __shared__ __align__(16) f16 Bs[128 * 32];
    int m0 = blockIdx.x * 128, n0 = blockIdx.y * 128;
    int t = threadIdx.x, lane = t & 63, w = t >> 6;
    int wr = w >> 1, wc = w & 1;
    f32x4 zero = {0.f, 0.f, 0.f, 0.f};
    f32x4 acc[4][4];
#pragma unroll
    for (int i = 0; i < 4; ++i)
#pragma unroll
        for (int j = 0; j < 4; ++j) acc[i][j] = zero;

    gemm_core(A, Bt, m0, n0, lane, w, wr, wc, As, Bs, acc);

#pragma unroll
    for (int j = 0; j < 4; ++j) {
        int n = n0 + wc * 64 + j * 16 + (lane & 15);
        float bv = bias[n];
#pragma unroll
        for (int i = 0; i < 4; ++i) {
            int m = m0 + wr * 64 + i * 16 + ((lane >> 4) << 2);
#pragma unroll
            for (int r = 0; r < 4; ++r) out[(size_t)(m + r) * 768 + n] = acc[i][j][r] + bv;
        }
    }
}

// ---------------- lsum: split-k partial row-sums, swapped QK^T (R11 proven) ----------------
__global__ __launch_bounds__(256) void k_lsum(const f16* __restrict__ Qh, const f16* __restrict__ Kf,
                                              float* __restrict__ lpart) {
    int qt = blockIdx.x, bh = blockIdx.y, kc = blockIdx.z;
    int q0 = qt * 64;
    int t = threadIdx.x, lane = t & 63, w = t >> 6;
    const f16* qbase = Qh + ((size_t)bh * 2048 + q0 + w * 16) * 64;
    const f16* kfb = Kf + (size_t)bh * 32 * 4096 + (size_t)lane * 8;

    f16x8 aq[2];
#pragma unroll
    for (int f = 0; f < 2; ++f)
        aq[f] = *(const f16x8*)(qbase + (size_t)(lane & 15) * 64 + f * 32 + (lane >> 4) * 8);
    f32x4 zero = {0.f, 0.f, 0.f, 0.f};

    auto LOADK = [&](f16x8* dst, int kt) {
        const f16* kp = kfb + (size_t)kt * 4096;
#pragma unroll
        for (int f = 0; f < 8; ++f) dst[f] = *(const f16x8*)(kp + f * 512);
    };
    auto QKTS = [&](const f16x8* kf, f32x4* s4) {   // swapped: A=K, B=Q
        __builtin_amdgcn_s_setprio(1);
#pragma unroll
        for (int s = 0; s < 4; ++s) {
            s4[s] = MFMA16(kf[2 * s], aq[0], zero);
            s4[s] = MFMA16(kf[2 * s + 1], aq[1], s4[s]);
        }
        __builtin_amdgcn_s_setprio(0);
    };

    f16x8 ka[8], kb2[8];
    float lsum = 0.f;
    int base = kc * 8;
    LOADK(ka, base);
    for (int i = 0; i < 8; i += 2) {
        f32x4 s4[4];
        LOADK(kb2, base + i + 1);
        QKTS(ka, s4);
#pragma unroll
        for (int s = 0; s < 4; ++s)
#pragma unroll
            for (int r = 0; r < 4; ++r) lsum += fexp2(s4[s][r]);
        LOADK(ka, base + ((i + 2) & 7));
        QKTS(kb2, s4);
#pragma unroll
        for (int s = 0; s < 4; ++s)
#pragma unroll
            for (int r = 0; r < 4; ++r) lsum += fexp2(s4[s][r]);
    }
    lsum += __shfl_xor(lsum, 16, 64);
    lsum += __shfl_xor(lsum, 32, 64);
    float* lp = lpart + (size_t)kc * 49152 + (size_t)bh * 2048 + q0 + w * 16;
    if (lane < 16) lp[lane] = lsum;
}

// ---------------- attention pass 2: LDS-staged K/V (shared by all 4 waves) ----------------
// R11 4-wave shape, but K/V tiles staged ONCE per block via global_load_lds (fragment-
// linear global layout -> linear LDS dest, rule-21 trivially both-sides-consistent),
// double-buffered, one __syncthreads per tile. Kills the 4x per-wave L2 re-read
// (1.57 GB -> 0.4 GB). Stores issued before PV; at each barrier the next tile's staging
// has had a full tile of compute to land.
__global__ __launch_bounds__(256, 3) void k_attn(const f16* __restrict__ Qh, const f16* __restrict__ Kf,
                                                 const f16* __restrict__ Vf,
                                                 const float* __restrict__ lpart,
                                                 float* __restrict__ attn, f16* __restrict__ valh) {
    __shared__ __align__(16) f16 KV[2][8192];        // [buf][K 4096 | V 4096] f16
    __shared__ __align__(16) float Ps32_all[4][16 * 68];
    int orig = blockIdx.x;
    int swz = (orig & 7) * 96 + (orig >> 3);   // 768 blocks, 8 XCDs, bijective
    int bh = swz >> 5, qt = swz & 31;
    int q0 = qt * 64;
    int t = threadIdx.x, lane = t & 63, w = t >> 6;

    const f16* qbase = Qh + ((size_t)bh * 2048 + q0 + w * 16) * 64;
    const f16* kfT = Kf + (size_t)bh * 32 * 4096;
    const f16* vfT = Vf + (size_t)bh * 32 * 4096;

    f16x8 aq[2];
#pragma unroll
    for (int f = 0; f < 2; ++f)
        aq[f] = *(const f16x8*)(qbase + (size_t)(lane & 15) * 64 + f * 32 + (lane >> 4) * 8);
    f32x4 zero = {0.f, 0.f, 0.f, 0.f};

    // scalar linv: this lane's q-row = q0 + w*16 + (lane&15)
    float linv;
    {
        size_t qoff = (size_t)bh * 2048 + q0 + w * 16 + (lane & 15);
        float s = 0.f;
#pragma unroll
        for (int kc = 0; kc < 4; ++kc) s += lpart[(size_t)kc * 49152 + qoff];
        linv = 1.0f / s;
    }

    // stage K/V tile kt into KV[buf]: each wave issues 2+2 gload16 (1KB each)
    auto STAGE = [&](int buf, int kt) {
        const f16* kp = kfT + (size_t)kt * 4096 + (size_t)lane * 8;
        const f16* vp = vfT + (size_t)kt * 4096 + (size_t)lane * 8;
        f16* kb = &KV[buf][0];
        f16* vb = &KV[buf][4096];
        gload16(kp + (2 * w) * 512, kb + (2 * w) * 512);
        gload16(kp + (2 * w + 1) * 512, kb + (2 * w + 1) * 512);
        gload16(vp + (2 * w) * 512, vb + (2 * w) * 512);
        gload16(vp + (2 * w + 1) * 512, vb + (2 * w + 1) * 512);
    };

    f32x4 accv[4];
#pragma unroll
    for (int j = 0; j < 4; ++j) accv[j] = zero;
    float* Ps = Ps32_all[w];   // wave-private 16 x 68 f32, [q][k]
    float* attn_base = attn + ((size_t)bh * 2048 + q0 + w * 16) * 2048;

    STAGE(0, 0);
    __syncthreads();
    int cur = 0;
    for (int kt = 0; kt < 32; ++kt) {
        if (kt < 31) STAGE(cur ^ 1, kt + 1);
        const f16* Ks = &KV[cur][0];
        const f16* Vs = &KV[cur][4096];
        // swapped QK^T from LDS K: lane holds S[k=s*16+(lane>>4)*4+r][q=lane&15]
        f32x4 s4[4];
        __builtin_amdgcn_s_setprio(1);
#pragma unroll
        for (int s = 0; s < 4; ++s) {
            f16x8 k0 = *(const f16x8*)(Ks + (2 * s) * 512 + lane * 8);
            f16x8 k1 = *(const f16x8*)(Ks + (2 * s + 1) * 512 + lane * 8);
            s4[s] = MFMA16(k0, aq[0], zero);
            s4[s] = MFMA16(k1, aq[1], s4[s]);
        }
        __builtin_amdgcn_s_setprio(0);
        // softmax -> Ps[q][k]: 4x ds_write_b128
#pragma unroll
        for (int s = 0; s < 4; ++s) {
            f32x4 pv;
#pragma unroll
            for (int r = 0; r < 4; ++r) pv[r] = fexp2(s4[s][r]) * linv;
            *(f32x4*)(Ps + (lane & 15) * 68 + s * 16 + (lane >> 4) * 4) = pv;
        }
        // PV A-fragment (f16) from the tile
        f16x8 pa[2];
#pragma unroll
        for (int hh = 0; hh < 2; ++hh) {
            const float* pr = Ps + (lane & 15) * 68 + hh * 32 + (lane >> 4) * 8;
            f32x4 lo = *(const f32x4*)(pr);
            f32x4 hi = *(const f32x4*)(pr + 4);
            f16x8 pf = {(f16)lo[0], (f16)lo[1], (f16)lo[2], (f16)lo[3],
                        (f16)hi[0], (f16)hi[1], (f16)hi[2], (f16)hi[3]};
            pa[hh] = pf;
        }
        // coalesced attention stores: 4x dwordx4 (256B runs per 16-lane group)
        float* ab = attn_base + kt * 64;
#pragma unroll
        for (int i = 0; i < 4; ++i) {
            int row = i * 4 + (lane >> 4);
            int col = (lane & 15) * 4;
            f32x4 v = *(const f32x4*)(Ps + row * 68 + col);
            *(f32x4*)(ab + (size_t)row * 2048 + col) = v;
        }
        // PV MFMA from LDS V
        __builtin_amdgcn_s_setprio(1);
#pragma unroll
        for (int jd = 0; jd < 4; ++jd) {
            f16x8 v0 = *(const f16x8*)(Vs + (2 * jd) * 512 + lane * 8);
            f16x8 v1 = *(const f16x8*)(Vs + (2 * jd + 1) * 512 + lane * 8);
            accv[jd] = MFMA16(pa[0], v0, accv[jd]);
            accv[jd] = MFMA16(pa[1], v1, accv[jd]);
        }
        __builtin_amdgcn_s_setprio(0);
        __syncthreads();
        cur ^= 1;
    }

    // epilogue: values -> valh [b*2048+t][h*64+d] f16
    int b = bh / 12, h = bh - b * 12;
#pragma unroll
    for (int j = 0; j < 4; ++j) {
#pragma unroll
        for (int r = 0; r < 4; ++r) {
            int rowg = b * 2048 + q0 + w * 16 + (lane >> 4) * 4 + r;
            int col = h * 64 + j * 16 + (lane & 15);
            valh[(size_t)rowg * 768 + col] = (f16)accv[j][r];
        }
    }
}

extern "C" void kernel_launch(void* const* d_in, const int* in_sizes, int n_in,
                              void* d_out, int out_size, void* d_ws, size_t ws_size,
                              hipStream_t stream) {
    const float* x = (const float*)d_in[0];
    const float* wqkv = (const float*)d_in[1];
    const float* bqkv = (const float*)d_in[2];
    const float* wo = (const float*)d_in[3];
    const float* bo = (const float*)d_in[4];

    float* out_o = (float*)d_out;                          // [2,2048,768] fp32
    float* out_attn = out_o + (size_t)2 * 2048 * 768;      // [2,12,2048,2048] fp32

    f16* ws = (f16*)d_ws;
    f16* xh = ws;                       // 3,145,728 f16
    f16* wqkv_t = xh + 3145728;         // [2304][768]
    f16* wo_t = wqkv_t + 1769472;       // [768][768]
    f16* Qh = wo_t + 589824;            // [bh][t][64], pre-scaled
    f16* Kf = Qh + 3145728;             // fragment-linear K
    f16* Vf = Kf + 3145728;             // fragment-linear V
    f16* valh = Vf + 3145728;           // [4096][768]
    float* lpart = (float*)(valh + 3145728);  // [4][24*2048] f32 split-k partials

    k_prep<<<3648, 256, 0, stream>>>(x, wqkv, wo, xh, wqkv_t, wo_t);
    k_qkv_gemm<<<dim3(32, 18), 256, 0, stream>>>(xh, wqkv_t, bqkv, Qh, Kf, Vf);
    k_lsum<<<dim3(32, 24, 4), 256, 0, stream>>>(Qh, Kf, lpart);
    k_attn<<<768, 256, 0, stream>>>(Qh, Kf, Vf, lpart, out_attn, valh);
    k_o_gemm<<<dim3(32, 6), 256, 0, stream>>>(valh, wo_t, bo, out_o);
}

// Round 18
// 182.601 us; speedup vs baseline: 1.1837x; 1.0318x over previous
//
#include <hip/hip_runtime.h>
#include <hip/hip_bf16.h>
#include <hip/hip_fp16.h>

typedef _Float16 f16;
typedef _Float16 f16x4 __attribute__((ext_vector_type(4)));
typedef _Float16 f16x8 __attribute__((ext_vector_type(8)));
typedef float f32x4 __attribute__((ext_vector_type(4)));

#define MFMA16(a, b, c) __builtin_amdgcn_mfma_f32_16x16x32_f16(a, b, c, 0, 0, 0)

__device__ __forceinline__ float fexp2(float x) {
#if __has_builtin(__builtin_amdgcn_exp2f)
    return __builtin_amdgcn_exp2f(x);
#else
    return exp2f(x);
#endif
}

typedef __attribute__((address_space(1))) const void gconst_t;
typedef __attribute__((address_space(3))) void lds_t;
__device__ __forceinline__ void gload16(const f16* g, f16* l) {
    __builtin_amdgcn_global_load_lds((gconst_t*)g, (lds_t*)l, 16, 0, 0);
}

// ---------------- fused prep: convert x + transpose wqkv + transpose wo ----------------
__device__ __forceinline__ void transpose_body(const float* __restrict__ in, f16* __restrict__ out,
                                               int K, int N, int n0, int k0, int t,
                                               f16 (*tile)[72]) {
    int r = t >> 2, cb = (t & 3) * 16;
    const float* src = in + (size_t)(k0 + r) * N + n0 + cb;
#pragma unroll
    for (int j = 0; j < 4; ++j) {
        float4 v = ((const float4*)src)[j];
        tile[r][cb + 4 * j + 0] = (f16)v.x;
        tile[r][cb + 4 * j + 1] = (f16)v.y;
        tile[r][cb + 4 * j + 2] = (f16)v.z;
        tile[r][cb + 4 * j + 3] = (f16)v.w;
    }
    __syncthreads();
    int nl = t >> 2, kb = (t & 3) * 16;
    f16* dst = out + (size_t)(n0 + nl) * K + k0 + kb;
#pragma unroll
    for (int j = 0; j < 2; ++j) {
        f16x8 o;
#pragma unroll
        for (int e = 0; e < 8; ++e) o[e] = tile[kb + 8 * j + e][nl];
        *(f16x8*)(dst + 8 * j) = o;
    }
}

__global__ __launch_bounds__(256) void k_prep(const float* __restrict__ x,
                                              const float* __restrict__ wqkv,
                                              const float* __restrict__ wo,
                                              f16* __restrict__ xh, f16* __restrict__ wqkv_t,
                                              f16* __restrict__ wo_t) {
    __shared__ f16 tile[64][72];
    int bid = blockIdx.x, t = threadIdx.x;
    if (bid < 3072) {
        int i = bid * 256 + t;
        float4 v = ((const float4*)x)[i];
        f16x4 o = {(f16)v.x, (f16)v.y, (f16)v.z, (f16)v.w};
        ((f16x4*)xh)[i] = o;
    } else if (bid < 3504) {
        int idx = bid - 3072;
        transpose_body(wqkv, wqkv_t, 768, 2304, (idx % 36) * 64, (idx / 36) * 64, t, tile);
    } else {
        int idx = bid - 3504;
        transpose_body(wo, wo_t, 768, 768, (idx % 12) * 64, (idx / 12) * 64, t, tile);
    }
}

// ---------------- shared GEMM core (R8): global_load_lds + XOR-swizzled LDS ----------------
__device__ __forceinline__ void gemm_core(const f16* __restrict__ A, const f16* __restrict__ Bt,
                                          int m0, int n0, int lane, int w, int wr, int wc,
                                          f16* As, f16* Bs, f32x4 acc[4][4]) {
    int prow = lane >> 2, pc = lane & 3;
    int lrow = prow ^ ((prow >> 2) & 1);
    int lcol = (pc ^ (lrow & 3)) * 8;
    int rsw = (lane & 7) << 3;
    for (int kt = 0; kt < 24; ++kt) {
        const f16* ab = A + (size_t)(m0 + w * 32 + lrow) * 768 + kt * 32 + lcol;
        const f16* bb = Bt + (size_t)(n0 + w * 32 + lrow) * 768 + kt * 32 + lcol;
        gload16(ab, As + (w * 32) * 32);
        gload16(ab + (size_t)16 * 768, As + (w * 32 + 16) * 32);
        gload16(bb, Bs + (w * 32) * 32);
        gload16(bb + (size_t)16 * 768, Bs + (w * 32 + 16) * 32);
        __syncthreads();
        f16x8 a[4], b[4];
#pragma unroll
        for (int i = 0; i < 4; ++i) {
            int idx = (wr * 64 + i * 16 + (lane & 15)) * 32 + (lane >> 4) * 8;
            a[i] = *(const f16x8*)(As + (idx ^ rsw));
        }
#pragma unroll
        for (int j = 0; j < 4; ++j) {
            int idx = (wc * 64 + j * 16 + (lane & 15)) * 32 + (lane >> 4) * 8;
            b[j] = *(const f16x8*)(Bs + (idx ^ rsw));
        }
#pragma unroll
        for (int i = 0; i < 4; ++i)
#pragma unroll
            for (int j = 0; j < 4; ++j) acc[i][j] = MFMA16(a[i], b[j], acc[i][j]);
        __syncthreads();
    }
}

// ---------------- QKV GEMM -> Qh (row layout), Kf/Vf (fragment-linear) ----------------
__global__ __launch_bounds__(256) void k_qkv_gemm(const f16* __restrict__ A, const f16* __restrict__ Bt,
                                                  const float* __restrict__ bias,
                                                  f16* __restrict__ Qh, f16* __restrict__ Kf,
                                                  f16* __restrict__ Vf) {
    __shared__ __align__(16) f16 As[128 * 32];
    __shared__ __align__(16) f16 Bs[128 * 32];
    int m0 = blockIdx.x * 128, n0 = blockIdx.y * 128;
    int t = threadIdx.x, lane = t & 63, w = t >> 6;
    int wr = w >> 1, wc = w & 1;
    f32x4 zero = {0.f, 0.f, 0.f, 0.f};
    f32x4 acc[4][4];
#pragma unroll
    for (int i = 0; i < 4; ++i)
#pragma unroll
        for (int j = 0; j < 4; ++j) acc[i][j] = zero;

    gemm_core(A, Bt, m0, n0, lane, w, wr, wc, As, Bs, acc);

    const float QSCALE = 0.18033688011112042f;  // 0.125 * log2(e)
#pragma unroll
    for (int j = 0; j < 4; ++j) {
        int n = n0 + wc * 64 + j * 16 + (lane & 15);
        int which = n / 768;
        int rem = n - which * 768;
        int h = rem >> 6, d = rem & 63;
        float bv = bias[n];
#pragma unroll
        for (int i = 0; i < 4; ++i) {
            int m = m0 + wr * 64 + i * 16 + ((lane >> 4) << 2);
            int bb = m >> 11, tt = m & 2047;
            int bh = bb * 12 + h;
            if (which == 2) {
                int kt = tt >> 6;
                int half = (tt & 63) >> 5, hi = (tt & 31) >> 3, e0 = tt & 7;
                int jd = d >> 4, lo = d & 15;
                size_t addr = (((size_t)bh * 32 + kt) * 8 + jd * 2 + half) * 512 +
                              (size_t)(hi * 16 + lo) * 8 + e0;
                f16x4 pk;
#pragma unroll
                for (int r = 0; r < 4; ++r) pk[r] = (f16)(acc[i][j][r] + bv);
                *(f16x4*)(Vf + addr) = pk;
            } else if (which == 0) {
#pragma unroll
                for (int r = 0; r < 4; ++r)
                    Qh[((size_t)bh * 2048 + tt + r) * 64 + d] = (f16)((acc[i][j][r] + bv) * QSCALE);
            } else {
                int half = d >> 5, hi = (d & 31) >> 3, e = d & 7;
#pragma unroll
                for (int r = 0; r < 4; ++r) {
                    int tr = tt + r;
                    int kt = tr >> 6, row = tr & 63;
                    int s = row >> 4, lo = row & 15;
                    size_t addr = (((size_t)bh * 32 + kt) * 8 + s * 2 + half) * 512 +
                                  (size_t)(hi * 16 + lo) * 8 + e;
                    Kf[addr] = (f16)(acc[i][j][r] + bv);
                }
            }
        }
    }
}

// ---------------- O GEMM ----------------
__global__ __launch_bounds__(256) void k_o_gemm(const f16* __restrict__ A, const f16* __restrict__ Bt,
                                                const float* __restrict__ bias,
                                                float* __restrict__ out) {
    __shared__ __align__(16) f16 As[128 * 32];
    __shared__ __align__(16) f16 Bs[128 * 32];
    int m0 = blockIdx.x * 128, n0 = blockIdx.y * 128;
    int t = threadIdx.x, lane = t & 63, w = t >> 6;
    int wr = w >> 1, wc = w & 1;
    f32x4 zero = {0.f, 0.f, 0.f, 0.f};
    f32x4 acc[4][4];
#pragma unroll
    for (int i = 0; i < 4; ++i)
#pragma unroll
        for (int j = 0; j < 4; ++j) acc[i][j] = zero;

    gemm_core(A, Bt, m0, n0, lane, w, wr, wc, As, Bs, acc);

#pragma unroll
    for (int j = 0; j < 4; ++j) {
        int n = n0 + wc * 64 + j * 16 + (lane & 15);
        float bv = bias[n];
#pragma unroll
        for (int i = 0; i < 4; ++i) {
            int m = m0 + wr * 64 + i * 16 + ((lane >> 4) << 2);
#pragma unroll
            for (int r = 0; r < 4; ++r) out[(size_t)(m + r) * 768 + n] = acc[i][j][r] + bv;
        }
    }
}

// ---------------- lsum: split-k partial row-sums; LDS-staged K (FULL 8KB tiles, dbuf) ----------------
// R16/R17 NaN root cause: STAGEK staged only half the 4096-f16 tile (1 gload/wave).
// Fixed: 2 gloads/wave x 4 waves = 4096 f16. Double-buffered with plain __syncthreads
// (R15-proven sync pattern).
__global__ __launch_bounds__(256) void k_lsum(const f16* __restrict__ Qh, const f16* __restrict__ Kf,
                                              float* __restrict__ lpart) {
    __shared__ __align__(16) f16 KR[2][4096];
    int qt = blockIdx.x, bh = blockIdx.y, kc = blockIdx.z;
    int q0 = qt * 64;
    int t = threadIdx.x, lane = t & 63, w = t >> 6;
    const f16* qbase = Qh + ((size_t)bh * 2048 + q0 + w * 16) * 64;
    const f16* kfT = Kf + (size_t)bh * 32 * 4096;

    f16x8 aq[2];
#pragma unroll
    for (int f = 0; f < 2; ++f)
        aq[f] = *(const f16x8*)(qbase + (size_t)(lane & 15) * 64 + f * 32 + (lane >> 4) * 8);
    f32x4 zero = {0.f, 0.f, 0.f, 0.f};

    int base = kc * 8;
    auto STAGEK = [&](f16* buf, int kt) {   // FULL tile: 2 gloads/wave (1KB each)
        const f16* kp = kfT + (size_t)kt * 4096 + (size_t)lane * 8;
        gload16(kp + (2 * w) * 512, buf + (2 * w) * 512);
        gload16(kp + (2 * w + 1) * 512, buf + (2 * w + 1) * 512);
    };
    float lsum = 0.f;
    auto COMP = [&](const f16* Ks) {        // swapped QK^T from LDS + exp accumulation
        f32x4 s4[4];
        __builtin_amdgcn_s_setprio(1);
#pragma unroll
        for (int s = 0; s < 4; ++s) {
            f16x8 k0 = *(const f16x8*)(Ks + (2 * s) * 512 + lane * 8);
            f16x8 k1 = *(const f16x8*)(Ks + (2 * s + 1) * 512 + lane * 8);
            s4[s] = MFMA16(k0, aq[0], zero);
            s4[s] = MFMA16(k1, aq[1], s4[s]);
        }
        __builtin_amdgcn_s_setprio(0);
#pragma unroll
        for (int s = 0; s < 4; ++s)
#pragma unroll
            for (int r = 0; r < 4; ++r) lsum += fexp2(s4[s][r]);
    };

    STAGEK(KR[0], base);
    __syncthreads();
    for (int i = 0; i < 8; ++i) {
        if (i < 7) STAGEK(KR[(i + 1) & 1], base + i + 1);
        COMP(KR[i & 1]);
        __syncthreads();
    }

    lsum += __shfl_xor(lsum, 16, 64);
    lsum += __shfl_xor(lsum, 32, 64);
    float* lp = lpart + (size_t)kc * 49152 + (size_t)bh * 2048 + q0 + w * 16;
    if (lane < 16) lp[lane] = lsum;
}

// ---------------- attention pass 2: LDS-staged K/V (R15-proven) + DEFERRED stores ----------------
// R15 structure exactly (KV[2] dbuf, __syncthreads per tile). One register-only change:
// tile kt's attention stores are held in 4 f32x4 regs and issued at the TOP of phase
// kt+1 -- so at each __syncthreads vmcnt-drain, outstanding stores have had a full
// compute phase to retire (drain tail ~0) instead of only PV-time.
__global__ __launch_bounds__(256, 3) void k_attn(const f16* __restrict__ Qh, const f16* __restrict__ Kf,
                                                 const f16* __restrict__ Vf,
                                                 const float* __restrict__ lpart,
                                                 float* __restrict__ attn, f16* __restrict__ valh) {
    __shared__ __align__(16) f16 KV[2][8192];        // [buf][K 4096 | V 4096]
    __shared__ __align__(16) float Ps32_all[4][16 * 68];
    int orig = blockIdx.x;
    int swz = (orig & 7) * 96 + (orig >> 3);   // 768 blocks, 8 XCDs, bijective
    int bh = swz >> 5, qt = swz & 31;
    int q0 = qt * 64;
    int t = threadIdx.x, lane = t & 63, w = t >> 6;

    const f16* qbase = Qh + ((size_t)bh * 2048 + q0 + w * 16) * 64;
    const f16* kfT = Kf + (size_t)bh * 32 * 4096;
    const f16* vfT = Vf + (size_t)bh * 32 * 4096;

    f16x8 aq[2];
#pragma unroll
    for (int f = 0; f < 2; ++f)
        aq[f] = *(const f16x8*)(qbase + (size_t)(lane & 15) * 64 + f * 32 + (lane >> 4) * 8);
    f32x4 zero = {0.f, 0.f, 0.f, 0.f};

    float linv;
    {
        size_t qoff = (size_t)bh * 2048 + q0 + w * 16 + (lane & 15);
        float s = 0.f;
#pragma unroll
        for (int kc = 0; kc < 4; ++kc) s += lpart[(size_t)kc * 49152 + qoff];
        linv = 1.0f / s;
    }

    auto STAGE = [&](f16* kb, int kt) {   // 4 gloads per wave (K 2 + V 2) = full tiles
        const f16* kp = kfT + (size_t)kt * 4096 + (size_t)lane * 8;
        const f16* vp = vfT + (size_t)kt * 4096 + (size_t)lane * 8;
        gload16(kp + (2 * w) * 512, kb + (2 * w) * 512);
        gload16(kp + (2 * w + 1) * 512, kb + (2 * w + 1) * 512);
        gload16(vp + (2 * w) * 512, kb + 4096 + (2 * w) * 512);
        gload16(vp + (2 * w + 1) * 512, kb + 4096 + (2 * w + 1) * 512);
    };

    f32x4 accv[4];
#pragma unroll
    for (int j = 0; j < 4; ++j) accv[j] = zero;
    float* Ps = Ps32_all[w];   // wave-private 16 x 68 f32, [q][k]
    float* attn_base = attn + ((size_t)bh * 2048 + q0 + w * 16) * 2048;
    f32x4 srow[4];             // deferred-store registers (tile kt's P rows)

    auto EMIT = [&](int kt) {  // issue deferred stores for tile kt (256B runs)
        float* ab = attn_base + kt * 64;
#pragma unroll
        for (int i = 0; i < 4; ++i)
            *(f32x4*)(ab + (size_t)(i * 4 + (lane >> 4)) * 2048 + (lane & 15) * 4) = srow[i];
    };

    auto COMPUTE = [&](const f16* buf, int kt) {
        const f16* Ks = buf;
        const f16* Vs = buf + 4096;
        // swapped QK^T from LDS K: lane holds S[k=s*16+(lane>>4)*4+r][q=lane&15]
        f32x4 s4[4];
        __builtin_amdgcn_s_setprio(1);
#pragma unroll
        for (int s = 0; s < 4; ++s) {
            f16x8 k0 = *(const f16x8*)(Ks + (2 * s) * 512 + lane * 8);
            f16x8 k1 = *(const f16x8*)(Ks + (2 * s + 1) * 512 + lane * 8);
            s4[s] = MFMA16(k0, aq[0], zero);
            s4[s] = MFMA16(k1, aq[1], s4[s]);
        }
        __builtin_amdgcn_s_setprio(0);
        // softmax -> Ps[q][k]: 4x ds_write_b128
#pragma unroll
        for (int s = 0; s < 4; ++s) {
            f32x4 pv;
#pragma unroll
            for (int r = 0; r < 4; ++r) pv[r] = fexp2(s4[s][r]) * linv;
            *(f32x4*)(Ps + (lane & 15) * 68 + s * 16 + (lane >> 4) * 4) = pv;
        }
        // PV A-fragment (f16) from the tile
        f16x8 pa[2];
#pragma unroll
        for (int hh = 0; hh < 2; ++hh) {
            const float* pr = Ps + (lane & 15) * 68 + hh * 32 + (lane >> 4) * 8;
            f32x4 lo = *(const f32x4*)(pr);
            f32x4 hi = *(const f32x4*)(pr + 4);
            f16x8 pf = {(f16)lo[0], (f16)lo[1], (f16)lo[2], (f16)lo[3],
                        (f16)hi[0], (f16)hi[1], (f16)hi[2], (f16)hi[3]};
            pa[hh] = pf;
        }
        // read store-rows into persistent regs (stores deferred to next phase)
#pragma unroll
        for (int i = 0; i < 4; ++i)
            srow[i] = *(const f32x4*)(Ps + (i * 4 + (lane >> 4)) * 68 + (lane & 15) * 4);
        // PV MFMA from LDS V
        __builtin_amdgcn_s_setprio(1);
#pragma unroll
        for (int jd = 0; jd < 4; ++jd) {
            f16x8 v0 = *(const f16x8*)(Vs + (2 * jd) * 512 + lane * 8);
            f16x8 v1 = *(const f16x8*)(Vs + (2 * jd + 1) * 512 + lane * 8);
            accv[jd] = MFMA16(pa[0], v0, accv[jd]);
            accv[jd] = MFMA16(pa[1], v1, accv[jd]);
        }
        __builtin_amdgcn_s_setprio(0);
    };

    STAGE(KV[0], 0);
    __syncthreads();
    int cur = 0;
    for (int kt = 0; kt < 32; ++kt) {
        if (kt < 31) STAGE(KV[cur ^ 1], kt + 1);
        if (kt > 0) EMIT(kt - 1);
        COMPUTE(KV[cur], kt);
        __syncthreads();
        cur ^= 1;
    }
    EMIT(31);

    // epilogue: values -> valh [b*2048+t][h*64+d] f16
    int b = bh / 12, h = bh - b * 12;
#pragma unroll
    for (int j = 0; j < 4; ++j) {
#pragma unroll
        for (int r = 0; r < 4; ++r) {
            int rowg = b * 2048 + q0 + w * 16 + (lane >> 4) * 4 + r;
            int col = h * 64 + j * 16 + (lane & 15);
            valh[(size_t)rowg * 768 + col] = (f16)accv[j][r];
        }
    }
}

extern "C" void kernel_launch(void* const* d_in, const int* in_sizes, int n_in,
                              void* d_out, int out_size, void* d_ws, size_t ws_size,
                              hipStream_t stream) {
    const float* x = (const float*)d_in[0];
    const float* wqkv = (const float*)d_in[1];
    const float* bqkv = (const float*)d_in[2];
    const float* wo = (const float*)d_in[3];
    const float* bo = (const float*)d_in[4];

    float* out_o = (float*)d_out;                          // [2,2048,768] fp32
    float* out_attn = out_o + (size_t)2 * 2048 * 768;      // [2,12,2048,2048] fp32

    f16* ws = (f16*)d_ws;
    f16* xh = ws;                       // 3,145,728 f16
    f16* wqkv_t = xh + 3145728;         // [2304][768]
    f16* wo_t = wqkv_t + 1769472;       // [768][768]
    f16* Qh = wo_t + 589824;            // [bh][t][64], pre-scaled
    f16* Kf = Qh + 3145728;             // fragment-linear K
    f16* Vf = Kf + 3145728;             // fragment-linear V
    f16* valh = Vf + 3145728;           // [4096][768]
    float* lpart = (float*)(valh + 3145728);  // [4][24*2048] f32 split-k partials

    k_prep<<<3648, 256, 0, stream>>>(x, wqkv, wo, xh, wqkv_t, wo_t);
    k_qkv_gemm<<<dim3(32, 18), 256, 0, stream>>>(xh, wqkv_t, bqkv, Qh, Kf, Vf);
    k_lsum<<<dim3(32, 24, 4), 256, 0, stream>>>(Qh, Kf, lpart);
    k_attn<<<768, 256, 0, stream>>>(Qh, Kf, Vf, lpart, out_attn, valh);
    k_o_gemm<<<dim3(32, 6), 256, 0, stream>>>(valh, wo_t, bo, out_o);
}